// Round 6
// baseline (217.566 us; speedup 1.0000x reference)
//
#include <hip/hip_runtime.h>

// SingleVQC via MFMA: each VQC block = RY(x) state build (real tensor product)
// followed by a FIXED 256x256 complex unitary U_v (depends only on theta) and
// Z-expvals. U_v is prebuilt (bf16) by simulating 256 basis columns with the
// verified shuffle-sim machinery; the main kernel does fused
// s-build -> bf16 GEMM (re,im) -> |Y|^2 -> signed reductions -> sin/cos, x4 VQCs.
//
// Amplitude bit convention (from reference reshape): qubit q <-> amp bit 7-q.
// R6 changes vs R5: FETCH/WRITE were invariant across R3-R5 -> traffic is the
// logical U restream (512 MB/dispatch), not spill. Halve it: 1024-thread
// blocks (16 waves = 2 row-groups x 8 col-groups), 128 rows/block, 256 blocks.
// Per-wave tile identical to R5 (64r x 32c, 64 acc regs) -- only the block
// shape changes.

typedef __attribute__((ext_vector_type(8))) short  bf16x8;
typedef __attribute__((ext_vector_type(4))) float  f32x4;

__device__ __forceinline__ ushort f2bf(float f) {
    unsigned u = __builtin_bit_cast(unsigned, f);
    u += 0x7fffu + ((u >> 16) & 1u);          // RNE
    return (ushort)(u >> 16);
}
__device__ __forceinline__ unsigned pack2(float a, float b) {
    return ((unsigned)f2bf(b) << 16) | (unsigned)f2bf(a);
}

// ---------------- gate-table prologue (unchanged, verified) ---------------
__global__ void gate_table_k(const float* __restrict__ theta,
                             float* __restrict__ gt) {
    int idx = blockIdx.x * blockDim.x + threadIdx.x;
    if (idx >= 128) return;
    float phi = theta[idx * 3 + 0];
    float th  = theta[idx * 3 + 1];
    float om  = theta[idx * 3 + 2];
    float ct = __cosf(0.5f * th),         st = __sinf(0.5f * th);
    float ca = __cosf(0.5f * (phi - om)), sa = __sinf(0.5f * (phi - om));
    float cb = __cosf(0.5f * (phi + om)), sb = __sinf(0.5f * (phi + om));
    float* g = gt + idx * 8;
    g[0] =  cb * ct;  g[1] = -sb * ct;
    g[2] = -ca * st;  g[3] = -sa * st;
    g[4] =  ca * st;  g[5] = -sa * st;
    g[6] =  cb * ct;  g[7] =  sb * ct;
}

// ---------------- U-build: one wave per (vqc, basis column) ---------------
__global__ void ubuild_k(const float* __restrict__ gt,
                         ushort* __restrict__ Ure, ushort* __restrict__ Uim) {
    const int lane = threadIdx.x & 63;
    const int wid  = threadIdx.x >> 6;
    const int wg   = blockIdx.x * 4 + wid;     // 0..1023
    const int v    = wg >> 8;                  // 0..3
    const int j    = wg & 255;                 // basis column

    float ar[4], ai[4];
#pragma unroll
    for (int r = 0; r < 4; ++r) {
        ar[r] = ((lane * 4 + r) == j) ? 1.0f : 0.0f;
        ai[r] = 0.0f;
    }

#pragma unroll
    for (int l = 0; l < 4; ++l) {
        const float* gl = gt + ((v * 4 + l) * 8) * 8;
#pragma unroll
        for (int q = 0; q < 8; ++q) {
            const float* g = gl + q * 8;
            const float g00r = g[0], g00i = g[1], g01r = g[2], g01i = g[3];
            const float g10r = g[4], g10i = g[5], g11r = g[6], g11i = g[7];
            const int b = 7 - q;
            if (b >= 2) {
                const int xm    = 1 << (b - 2);
                const int mybit = (lane >> (b - 2)) & 1;
                const float cAr = mybit ? g11r : g00r;
                const float cAi = mybit ? g11i : g00i;
                const float cBr = mybit ? g10r : g01r;
                const float cBi = mybit ? g10i : g01i;
#pragma unroll
                for (int r = 0; r < 4; ++r) {
                    const float oR = __shfl_xor(ar[r], xm, 64);
                    const float oI = __shfl_xor(ai[r], xm, 64);
                    const float nR = cAr * ar[r] - cAi * ai[r] + cBr * oR - cBi * oI;
                    const float nI = cAr * ai[r] + cAi * ar[r] + cBr * oI + cBi * oR;
                    ar[r] = nR; ai[r] = nI;
                }
            } else {
                const int step = 1 << b;
#pragma unroll
                for (int r0 = 0; r0 < 4; ++r0) {
                    if ((r0 & step) == 0) {
                        const int r1 = r0 | step;
                        const float a0r = ar[r0], a0i = ai[r0];
                        const float a1r = ar[r1], a1i = ai[r1];
                        ar[r0] = g00r * a0r - g00i * a0i + g01r * a1r - g01i * a1i;
                        ai[r0] = g00r * a0i + g00i * a0r + g01r * a1i + g01i * a1r;
                        ar[r1] = g10r * a0r - g10i * a0i + g11r * a1r - g11i * a1i;
                        ai[r1] = g10r * a0i + g10i * a0r + g11r * a1i + g11i * a1r;
                    }
                }
            }
        }
        const int roff = l + 1;
#pragma unroll
        for (int q = 0; q < 8; ++q) {
            const int t  = (q + roff) & 7;
            const int bc = 7 - q;
            const int bt = 7 - t;
            if (bt >= 2) {
                const int xm = 1 << (bt - 2);
                if (bc >= 2) {
                    const int cbit = (lane >> (bc - 2)) & 1;
#pragma unroll
                    for (int r = 0; r < 4; ++r) {
                        const float oR = __shfl_xor(ar[r], xm, 64);
                        const float oI = __shfl_xor(ai[r], xm, 64);
                        ar[r] = cbit ? oR : ar[r];
                        ai[r] = cbit ? oI : ai[r];
                    }
                } else {
#pragma unroll
                    for (int r = 0; r < 4; ++r) {
                        if ((r >> bc) & 1) {
                            ar[r] = __shfl_xor(ar[r], xm, 64);
                            ai[r] = __shfl_xor(ai[r], xm, 64);
                        }
                    }
                }
            } else {
                const int step = 1 << bt;
                if (bc >= 2) {
                    const int cbit = (lane >> (bc - 2)) & 1;
#pragma unroll
                    for (int r0 = 0; r0 < 4; ++r0) {
                        if (((r0 >> bt) & 1) == 0) {
                            const int r1 = r0 | step;
                            const float t0r = cbit ? ar[r1] : ar[r0];
                            const float t0i = cbit ? ai[r1] : ai[r0];
                            const float t1r = cbit ? ar[r0] : ar[r1];
                            const float t1i = cbit ? ai[r0] : ai[r1];
                            ar[r0] = t0r; ai[r0] = t0i;
                            ar[r1] = t1r; ai[r1] = t1i;
                        }
                    }
                } else {
#pragma unroll
                    for (int r0 = 0; r0 < 4; ++r0) {
                        if (((r0 >> bc) & 1) == 1 && ((r0 >> bt) & 1) == 0) {
                            const int r1 = r0 | step;
                            float tr = ar[r0]; ar[r0] = ar[r1]; ar[r1] = tr;
                            float ti = ai[r0]; ai[r0] = ai[r1]; ai[r1] = ti;
                        }
                    }
                }
            }
        }
    }

    // store column j of U_v as bf16, row-major [i][j]
    ushort* ur = Ure + v * 65536;
    ushort* ui = Uim + v * 65536;
#pragma unroll
    for (int r = 0; r < 4; ++r) {
        const int i = lane * 4 + r;
        ur[i * 256 + j] = f2bf(ar[r]);
        ui[i * 256 + j] = f2bf(ai[r]);
    }
}

// ---------------- fused main kernel ---------------------------------------
// 256 blocks x 1024 threads; block owns 128 batch rows through all 4 VQCs.
// Wave w (0..15): rg = w>>3 (64-row group), cg = w&7 (32-col group).
__global__ __launch_bounds__(1024, 4)
void vqc_mfma_k(const float* __restrict__ xg,
                const ushort* __restrict__ Ure, const ushort* __restrict__ Uim,
                float* __restrict__ out) {
    __shared__ ushort s_lds[128 * 256];       // 64 KB, XOR-swizzled bf16
    __shared__ float  ex_part[8][128][9];     // 36 KB (pad 9)
    __shared__ float  x_lds[128][8];          // 4 KB

    const int tid  = threadIdx.x;
    const int lane = tid & 63;
    const int w    = tid >> 6;       // 0..15
    const int rg   = w >> 3;         // row group: rows rg*64 .. rg*64+63
    const int cg   = w & 7;          // col group: cols cg*32 .. cg*32+31
    const int l15  = lane & 15;
    const int g4   = lane >> 4;
    const int rowbase = blockIdx.x * 128;

    // butterfly signs for lane bits 0..3
    const float sg0 = (lane & 1) ? -1.f : 1.f;
    const float sg1 = (lane & 2) ? -1.f : 1.f;
    const float sg2 = (lane & 4) ? -1.f : 1.f;
    const float sg3 = (lane & 8) ? -1.f : 1.f;

    // initial x into LDS (1024 floats, one per thread)
    ((float*)x_lds)[tid] = xg[(size_t)rowbase * 8 + tid];
    __syncthreads();

    const int srow = tid >> 3;     // s-build: 8 threads per row (128 rows)
    const int sc   = tid & 7;      // 32-amp chunk (amp bits 7,6,5 = qubits 0,1,2)

    for (int v = 0; v < 4; ++v) {
        // ---- (a) build s[row][k] = prod_b f_b(k_b), bf16 swizzled ----
        {
            float hc[8], hs[8];
#pragma unroll
            for (int q = 0; q < 8; ++q) {
                float h = 0.5f * x_lds[srow][q];
                hs[q] = __sinf(h); hc[q] = __cosf(h);
            }
            float arr[32];
            arr[0] = (((sc >> 2) & 1) ? hs[0] : hc[0])
                   * (((sc >> 1) & 1) ? hs[1] : hc[1])
                   * (((sc     ) & 1) ? hs[2] : hc[2]);
#define LVL(LEN, FC, FS)                                            \
            _Pragma("unroll")                                       \
            for (int m = (LEN) - 1; m >= 0; --m) {                  \
                arr[2*m+1] = arr[m] * (FS);                         \
                arr[2*m]   = arr[m] * (FC);                         \
            }
            LVL(1,  hc[3], hs[3])   // amp bit4  (q3)
            LVL(2,  hc[4], hs[4])   // bit3      (q4)
            LVL(4,  hc[5], hs[5])   // bit2      (q5)
            LVL(8,  hc[6], hs[6])   // bit1      (q6)
            LVL(16, hc[7], hs[7])   // bit0      (q7)
#undef LVL
            char* sb = (char*)s_lds + srow * 512;
            const int swz = (srow & 7) << 4;
#pragma unroll
            for (int j = 0; j < 4; ++j) {
                uint4 wv;
                wv.x = pack2(arr[j*8+0], arr[j*8+1]);
                wv.y = pack2(arr[j*8+2], arr[j*8+3]);
                wv.z = pack2(arr[j*8+4], arr[j*8+5]);
                wv.w = pack2(arr[j*8+6], arr[j*8+7]);
                *(uint4*)(sb + ((sc * 64 + j * 16) ^ swz)) = wv;
            }
        }
        __syncthreads();

        // ---- (b) GEMM: per wave, Y(re,im)[64 rows x 32 cols] = s @ U^T ----
        const ushort* Ur = Ure + v * 65536;
        const ushort* Ui = Uim + v * 65536;
        f32x4 accr[4][2], acci[4][2];
#pragma unroll
        for (int rb = 0; rb < 4; ++rb)
#pragma unroll
            for (int cb = 0; cb < 2; ++cb) {
                accr[rb][cb] = (f32x4){0.f, 0.f, 0.f, 0.f};
                acci[rb][cb] = (f32x4){0.f, 0.f, 0.f, 0.f};
            }

#pragma unroll
        for (int ks = 0; ks < 8; ++ks) {
            bf16x8 afr[4];
#pragma unroll
            for (int rb = 0; rb < 4; ++rb) {
                const int row = rg * 64 + rb * 16 + l15;
                const int off = row * 512 + (((ks * 64) + (g4 << 4)) ^ ((row & 7) << 4));
                afr[rb] = *(const bf16x8*)((const char*)s_lds + off);
            }
#pragma unroll
            for (int cb = 0; cb < 2; ++cb) {
                const int col = cg * 32 + cb * 16 + l15;
                const int off = col * 256 + ks * 32 + (g4 << 3);
                const bf16x8 bfr = *(const bf16x8*)(Ur + off);
                const bf16x8 bfi = *(const bf16x8*)(Ui + off);
#pragma unroll
                for (int rb = 0; rb < 4; ++rb) {
                    accr[rb][cb] = __builtin_amdgcn_mfma_f32_16x16x32_bf16(
                        afr[rb], bfr, accr[rb][cb], 0, 0, 0);
                    acci[rb][cb] = __builtin_amdgcn_mfma_f32_16x16x32_bf16(
                        afr[rb], bfi, acci[rb][cb], 0, 0, 0);
                }
            }
        }

        // ---- (c) p = |Y|^2; in-thread cb combine + carried signed butterfly
        // col bits: [3:0]=l15, [4]=cb, [7:5]=cg.  qubit q <-> col bit 7-q.
#pragma unroll
        for (int rb = 0; rb < 4; ++rb) {
#pragma unroll
            for (int r = 0; r < 4; ++r) {
                const float p0 = accr[rb][0][r]*accr[rb][0][r] + acci[rb][0][r]*acci[rb][0][r];
                const float p1 = accr[rb][1][r]*accr[rb][1][r] + acci[rb][1][r]*acci[rb][1][r];
                float T0 = p0 + p1;      // total (feeds q0..q2 via cg-signs, and diffs)
                float T1 = p0 - p1;      // signed cb -> col bit4 -> q3
                float d0, d1, d2, d3, pt;
                // step0 (mask1, col bit0 -> q7)
                pt = __shfl_xor(T0, 1, 64); d0 = sg0 * (T0 - pt); T0 += pt;
                pt = __shfl_xor(T1, 1, 64); T1 += pt;
                // step1 (mask2 -> q6)
                pt = __shfl_xor(T0, 2, 64); d1 = sg1 * (T0 - pt); T0 += pt;
                pt = __shfl_xor(T1, 2, 64); T1 += pt;
                pt = __shfl_xor(d0, 2, 64); d0 += pt;
                // step2 (mask4 -> q5)
                pt = __shfl_xor(T0, 4, 64); d2 = sg2 * (T0 - pt); T0 += pt;
                pt = __shfl_xor(T1, 4, 64); T1 += pt;
                pt = __shfl_xor(d0, 4, 64); d0 += pt;
                pt = __shfl_xor(d1, 4, 64); d1 += pt;
                // step3 (mask8 -> q4)
                pt = __shfl_xor(T0, 8, 64); d3 = sg3 * (T0 - pt); T0 += pt;
                pt = __shfl_xor(T1, 8, 64); T1 += pt;
                pt = __shfl_xor(d0, 8, 64); d0 += pt;
                pt = __shfl_xor(d1, 8, 64); d1 += pt;
                pt = __shfl_xor(d2, 8, 64); d2 += pt;
                if (l15 == 0) {
                    const int row = rg * 64 + rb * 16 + g4 * 4 + r;
                    float* e = &ex_part[cg][row][0];
                    e[0] = T0; e[1] = T0; e[2] = T0; e[3] = T1;
                    e[4] = d3; e[5] = d2; e[6] = d1; e[7] = d0;
                }
            }
        }
        __syncthreads();

        // ---- (d) combine col-groups: q0 sign by cg bit2, q1 by cg bit1, q2 by cg bit0
        {
            const int row = tid >> 3, q = tid & 7;
            const bool b2 = (q == 0), b1 = (q == 1), b0 = (q == 2);
            float acc = 0.f;
#pragma unroll
            for (int g = 0; g < 8; ++g) {
                const float e = ex_part[g][row][q];
                const bool neg = (b2 && (g & 4)) || (b1 && (g & 2)) || (b0 && (g & 1));
                acc += neg ? -e : e;
            }
            x_lds[row][q] = acc;
        }
        __syncthreads();
    }

    // output = H[:,4] * float(pi - eps_f32)
    const float MULT = 3.14159253589793f;
    if (tid < 128) out[rowbase + tid] = x_lds[tid][4] * MULT;
}

// ---------------- launcher ------------------------------------------------
extern "C" void kernel_launch(void* const* d_in, const int* in_sizes, int n_in,
                              void* d_out, int out_size, void* d_ws, size_t ws_size,
                              hipStream_t stream) {
    const float* x     = (const float*)d_in[0];   // (32768, 8) fp32
    const float* theta = (const float*)d_in[1];   // (4, 4, 8, 3) fp32
    float* out = (float*)d_out;                   // (32768,) fp32

    char*   ws  = (char*)d_ws;
    float*  gt  = (float*)ws;                         // 4 KB
    ushort* Ure = (ushort*)(ws + 4096);               // 512 KB
    ushort* Uim = (ushort*)(ws + 4096 + 524288);      // 512 KB

    gate_table_k<<<1, 128, 0, stream>>>(theta, gt);
    ubuild_k<<<256, 256, 0, stream>>>(gt, Ure, Uim);
    vqc_mfma_k<<<256, 1024, 0, stream>>>(x, Ure, Uim, out);
}

// Round 7
// 157.201 us; speedup vs baseline: 1.3840x; 1.3840x over previous
//
#include <hip/hip_runtime.h>

// SingleVQC via MFMA: each VQC block = RY(x) state build (real tensor product)
// followed by a FIXED 256x256 complex unitary U_v (depends only on theta) and
// Z-expvals. U_v is prebuilt (bf16); main kernel: fused s-build -> bf16 GEMM
// (re,im) -> |Y|^2 -> signed reductions -> sin/cos, x4 VQCs.
//
// R7 vs R5 (best, 129us): U stored FRAGMENT-MAJOR  Upack[v][ks][g4][col][8]
// so each wave B-load = 4 contiguous 256B segments instead of 64 distinct
// 512B-strided lines (16x fewer L2 transactions). R3-R6 showed FETCH/WRITE
// invariant under all logical changes => artifact; real cost = uncoalesced
// U loads (address-pipe + latency). Everything else identical to R5.

typedef __attribute__((ext_vector_type(8))) short  bf16x8;
typedef __attribute__((ext_vector_type(4))) float  f32x4;

__device__ __forceinline__ ushort f2bf(float f) {
    unsigned u = __builtin_bit_cast(unsigned, f);
    u += 0x7fffu + ((u >> 16) & 1u);          // RNE
    return (ushort)(u >> 16);
}
__device__ __forceinline__ unsigned pack2(float a, float b) {
    return ((unsigned)f2bf(b) << 16) | (unsigned)f2bf(a);
}

// ---------------- gate-table prologue (unchanged, verified) ---------------
__global__ void gate_table_k(const float* __restrict__ theta,
                             float* __restrict__ gt) {
    int idx = blockIdx.x * blockDim.x + threadIdx.x;
    if (idx >= 128) return;
    float phi = theta[idx * 3 + 0];
    float th  = theta[idx * 3 + 1];
    float om  = theta[idx * 3 + 2];
    float ct = __cosf(0.5f * th),         st = __sinf(0.5f * th);
    float ca = __cosf(0.5f * (phi - om)), sa = __sinf(0.5f * (phi - om));
    float cb = __cosf(0.5f * (phi + om)), sb = __sinf(0.5f * (phi + om));
    float* g = gt + idx * 8;
    g[0] =  cb * ct;  g[1] = -sb * ct;
    g[2] = -ca * st;  g[3] = -sa * st;
    g[4] =  ca * st;  g[5] = -sa * st;
    g[6] =  cb * ct;  g[7] =  sb * ct;
}

// ---------------- U-build: one wave per (vqc, basis column) ---------------
// Computes column j of U_v (thread holds U[col=lane*4+r][k=j]); stores into
// fragment-major Upack[v][ks=k>>5][g4=(k>>3)&3][col][e=k&7], 65536 ush/VQC.
__global__ void ubuild_k(const float* __restrict__ gt,
                         ushort* __restrict__ Upr, ushort* __restrict__ Upi) {
    const int lane = threadIdx.x & 63;
    const int wid  = threadIdx.x >> 6;
    const int wg   = blockIdx.x * 4 + wid;     // 0..1023
    const int v    = wg >> 8;                  // 0..3
    const int j    = wg & 255;                 // basis column = k index

    float ar[4], ai[4];
#pragma unroll
    for (int r = 0; r < 4; ++r) {
        ar[r] = ((lane * 4 + r) == j) ? 1.0f : 0.0f;
        ai[r] = 0.0f;
    }

#pragma unroll
    for (int l = 0; l < 4; ++l) {
        const float* gl = gt + ((v * 4 + l) * 8) * 8;
#pragma unroll
        for (int q = 0; q < 8; ++q) {
            const float* g = gl + q * 8;
            const float g00r = g[0], g00i = g[1], g01r = g[2], g01i = g[3];
            const float g10r = g[4], g10i = g[5], g11r = g[6], g11i = g[7];
            const int b = 7 - q;
            if (b >= 2) {
                const int xm    = 1 << (b - 2);
                const int mybit = (lane >> (b - 2)) & 1;
                const float cAr = mybit ? g11r : g00r;
                const float cAi = mybit ? g11i : g00i;
                const float cBr = mybit ? g10r : g01r;
                const float cBi = mybit ? g10i : g01i;
#pragma unroll
                for (int r = 0; r < 4; ++r) {
                    const float oR = __shfl_xor(ar[r], xm, 64);
                    const float oI = __shfl_xor(ai[r], xm, 64);
                    const float nR = cAr * ar[r] - cAi * ai[r] + cBr * oR - cBi * oI;
                    const float nI = cAr * ai[r] + cAi * ar[r] + cBr * oI + cBi * oR;
                    ar[r] = nR; ai[r] = nI;
                }
            } else {
                const int step = 1 << b;
#pragma unroll
                for (int r0 = 0; r0 < 4; ++r0) {
                    if ((r0 & step) == 0) {
                        const int r1 = r0 | step;
                        const float a0r = ar[r0], a0i = ai[r0];
                        const float a1r = ar[r1], a1i = ai[r1];
                        ar[r0] = g00r * a0r - g00i * a0i + g01r * a1r - g01i * a1i;
                        ai[r0] = g00r * a0i + g00i * a0r + g01r * a1i + g01i * a1r;
                        ar[r1] = g10r * a0r - g10i * a0i + g11r * a1r - g11i * a1i;
                        ai[r1] = g10r * a0i + g10i * a0r + g11r * a1i + g11i * a1r;
                    }
                }
            }
        }
        const int roff = l + 1;
#pragma unroll
        for (int q = 0; q < 8; ++q) {
            const int t  = (q + roff) & 7;
            const int bc = 7 - q;
            const int bt = 7 - t;
            if (bt >= 2) {
                const int xm = 1 << (bt - 2);
                if (bc >= 2) {
                    const int cbit = (lane >> (bc - 2)) & 1;
#pragma unroll
                    for (int r = 0; r < 4; ++r) {
                        const float oR = __shfl_xor(ar[r], xm, 64);
                        const float oI = __shfl_xor(ai[r], xm, 64);
                        ar[r] = cbit ? oR : ar[r];
                        ai[r] = cbit ? oI : ai[r];
                    }
                } else {
#pragma unroll
                    for (int r = 0; r < 4; ++r) {
                        if ((r >> bc) & 1) {
                            ar[r] = __shfl_xor(ar[r], xm, 64);
                            ai[r] = __shfl_xor(ai[r], xm, 64);
                        }
                    }
                }
            } else {
                const int step = 1 << bt;
                if (bc >= 2) {
                    const int cbit = (lane >> (bc - 2)) & 1;
#pragma unroll
                    for (int r0 = 0; r0 < 4; ++r0) {
                        if (((r0 >> bt) & 1) == 0) {
                            const int r1 = r0 | step;
                            const float t0r = cbit ? ar[r1] : ar[r0];
                            const float t0i = cbit ? ai[r1] : ai[r0];
                            const float t1r = cbit ? ar[r0] : ar[r1];
                            const float t1i = cbit ? ai[r0] : ai[r1];
                            ar[r0] = t0r; ai[r0] = t0i;
                            ar[r1] = t1r; ai[r1] = t1i;
                        }
                    }
                } else {
#pragma unroll
                    for (int r0 = 0; r0 < 4; ++r0) {
                        if (((r0 >> bc) & 1) == 1 && ((r0 >> bt) & 1) == 0) {
                            const int r1 = r0 | step;
                            float tr = ar[r0]; ar[r0] = ar[r1]; ar[r1] = tr;
                            float ti = ai[r0]; ai[r0] = ai[r1]; ai[r1] = ti;
                        }
                    }
                }
            }
        }
    }

    // fragment-major store: Upack[v][ks][g4p][col][e], k = j
    const int ks  = j >> 5;
    const int g4p = (j >> 3) & 3;
    const int e   = j & 7;
    ushort* ur = Upr + (size_t)v * 65536 + ((ks * 4 + g4p) * 256) * 8 + e;
    ushort* ui = Upi + (size_t)v * 65536 + ((ks * 4 + g4p) * 256) * 8 + e;
#pragma unroll
    for (int r = 0; r < 4; ++r) {
        const int col = lane * 4 + r;
        ur[col * 8] = f2bf(ar[r]);
        ui[col * 8] = f2bf(ai[r]);
    }
}

// ---------------- fused main kernel ---------------------------------------
// 512 blocks x 512 threads; block owns 64 batch rows through all 4 VQCs.
// Wave w (0..7) owns 32 output cols (cols w*32..w*32+31), re AND im.
__global__ __launch_bounds__(512, 4)
void vqc_mfma_k(const float* __restrict__ xg,
                const ushort* __restrict__ Upr, const ushort* __restrict__ Upi,
                float* __restrict__ out) {
    __shared__ ushort s_lds[64 * 256];        // 32 KB, XOR-swizzled bf16
    __shared__ float  ex_part[8][64][9];      // 18 KB (pad 9 breaks stride-8)
    __shared__ float  x_lds[64][8];           // 2 KB

    const int tid  = threadIdx.x;
    const int lane = tid & 63;
    const int w    = tid >> 6;       // col group: cols w*32 .. w*32+31
    const int l15  = lane & 15;
    const int g4   = lane >> 4;
    const int rowbase = blockIdx.x * 64;

    // butterfly signs for lane bits 0..3
    const float sg0 = (lane & 1) ? -1.f : 1.f;
    const float sg1 = (lane & 2) ? -1.f : 1.f;
    const float sg2 = (lane & 4) ? -1.f : 1.f;
    const float sg3 = (lane & 8) ? -1.f : 1.f;

    // initial x into LDS (512 floats, one per thread)
    ((float*)x_lds)[tid] = xg[(size_t)rowbase * 8 + tid];
    __syncthreads();

    const int srow = tid >> 3;     // s-build: 8 threads per row
    const int sc   = tid & 7;      // 32-amp chunk (amp bits 7,6,5 = qubits 0,1,2)

    for (int v = 0; v < 4; ++v) {
        // ---- (a) build s[row][k] = prod_b f_b(k_b), bf16 swizzled ----
        {
            float hc[8], hs[8];
#pragma unroll
            for (int q = 0; q < 8; ++q) {
                float h = 0.5f * x_lds[srow][q];
                hs[q] = __sinf(h); hc[q] = __cosf(h);
            }
            float arr[32];
            arr[0] = (((sc >> 2) & 1) ? hs[0] : hc[0])
                   * (((sc >> 1) & 1) ? hs[1] : hc[1])
                   * (((sc     ) & 1) ? hs[2] : hc[2]);
#define LVL(LEN, FC, FS)                                            \
            _Pragma("unroll")                                       \
            for (int m = (LEN) - 1; m >= 0; --m) {                  \
                arr[2*m+1] = arr[m] * (FS);                         \
                arr[2*m]   = arr[m] * (FC);                         \
            }
            LVL(1,  hc[3], hs[3])   // amp bit4  (q3)
            LVL(2,  hc[4], hs[4])   // bit3      (q4)
            LVL(4,  hc[5], hs[5])   // bit2      (q5)
            LVL(8,  hc[6], hs[6])   // bit1      (q6)
            LVL(16, hc[7], hs[7])   // bit0      (q7)
#undef LVL
            char* sb = (char*)s_lds + srow * 512;
            const int swz = (srow & 7) << 4;
#pragma unroll
            for (int j = 0; j < 4; ++j) {
                uint4 wv;
                wv.x = pack2(arr[j*8+0], arr[j*8+1]);
                wv.y = pack2(arr[j*8+2], arr[j*8+3]);
                wv.z = pack2(arr[j*8+4], arr[j*8+5]);
                wv.w = pack2(arr[j*8+6], arr[j*8+7]);
                *(uint4*)(sb + ((sc * 64 + j * 16) ^ swz)) = wv;
            }
        }
        __syncthreads();

        // ---- (b) GEMM: per wave, Y(re,im)[64 rows x 32 cols] = s @ U^T ----
        // B-frag loads now coalesced: Upack[v][ks][g4][col][8].
        const ushort* Ur = Upr + (size_t)v * 65536;
        const ushort* Ui = Upi + (size_t)v * 65536;
        f32x4 accr[4][2], acci[4][2];
#pragma unroll
        for (int rb = 0; rb < 4; ++rb)
#pragma unroll
            for (int cb = 0; cb < 2; ++cb) {
                accr[rb][cb] = (f32x4){0.f, 0.f, 0.f, 0.f};
                acci[rb][cb] = (f32x4){0.f, 0.f, 0.f, 0.f};
            }

#pragma unroll
        for (int ks = 0; ks < 8; ++ks) {
            bf16x8 afr[4];
#pragma unroll
            for (int rb = 0; rb < 4; ++rb) {
                const int row = rb * 16 + l15;
                const int off = row * 512 + (((ks * 64) + (g4 << 4)) ^ ((row & 7) << 4));
                afr[rb] = *(const bf16x8*)((const char*)s_lds + off);
            }
#pragma unroll
            for (int cb = 0; cb < 2; ++cb) {
                const int col  = w * 32 + cb * 16 + l15;
                const int boff = ((ks * 4 + g4) * 256 + col) * 8;
                const bf16x8 bfr = *(const bf16x8*)(Ur + boff);
                const bf16x8 bfi = *(const bf16x8*)(Ui + boff);
#pragma unroll
                for (int rb = 0; rb < 4; ++rb) {
                    accr[rb][cb] = __builtin_amdgcn_mfma_f32_16x16x32_bf16(
                        afr[rb], bfr, accr[rb][cb], 0, 0, 0);
                    acci[rb][cb] = __builtin_amdgcn_mfma_f32_16x16x32_bf16(
                        afr[rb], bfi, acci[rb][cb], 0, 0, 0);
                }
            }
        }

        // ---- (c) p = |Y|^2; in-thread cb combine + carried signed butterfly
        // col bits: [3:0]=l15, [4]=cb, [7:5]=w.  qubit q <-> col bit 7-q.
#pragma unroll
        for (int rb = 0; rb < 4; ++rb) {
#pragma unroll
            for (int r = 0; r < 4; ++r) {
                const float p0 = accr[rb][0][r]*accr[rb][0][r] + acci[rb][0][r]*acci[rb][0][r];
                const float p1 = accr[rb][1][r]*accr[rb][1][r] + acci[rb][1][r]*acci[rb][1][r];
                float T0 = p0 + p1;      // total (feeds q0..q2 via w-signs, and diffs)
                float T1 = p0 - p1;      // signed cb -> col bit4 -> q3
                float d0, d1, d2, d3, pt;
                // step0 (mask1, col bit0 -> q7)
                pt = __shfl_xor(T0, 1, 64); d0 = sg0 * (T0 - pt); T0 += pt;
                pt = __shfl_xor(T1, 1, 64); T1 += pt;
                // step1 (mask2 -> q6)
                pt = __shfl_xor(T0, 2, 64); d1 = sg1 * (T0 - pt); T0 += pt;
                pt = __shfl_xor(T1, 2, 64); T1 += pt;
                pt = __shfl_xor(d0, 2, 64); d0 += pt;
                // step2 (mask4 -> q5)
                pt = __shfl_xor(T0, 4, 64); d2 = sg2 * (T0 - pt); T0 += pt;
                pt = __shfl_xor(T1, 4, 64); T1 += pt;
                pt = __shfl_xor(d0, 4, 64); d0 += pt;
                pt = __shfl_xor(d1, 4, 64); d1 += pt;
                // step3 (mask8 -> q4)
                pt = __shfl_xor(T0, 8, 64); d3 = sg3 * (T0 - pt); T0 += pt;
                pt = __shfl_xor(T1, 8, 64); T1 += pt;
                pt = __shfl_xor(d0, 8, 64); d0 += pt;
                pt = __shfl_xor(d1, 8, 64); d1 += pt;
                pt = __shfl_xor(d2, 8, 64); d2 += pt;
                if (l15 == 0) {
                    const int row = rb * 16 + g4 * 4 + r;
                    float* e = &ex_part[w][row][0];
                    e[0] = T0; e[1] = T0; e[2] = T0; e[3] = T1;
                    e[4] = d3; e[5] = d2; e[6] = d1; e[7] = d0;
                }
            }
        }
        __syncthreads();

        // ---- (d) combine col-groups: q0 sign by w bit2, q1 by w bit1, q2 by w bit0
        {
            const int row = tid >> 3, q = tid & 7;
            const bool b2 = (q == 0), b1 = (q == 1), b0 = (q == 2);
            float acc = 0.f;
#pragma unroll
            for (int g = 0; g < 8; ++g) {
                const float e = ex_part[g][row][q];
                const bool neg = (b2 && (g & 4)) || (b1 && (g & 2)) || (b0 && (g & 1));
                acc += neg ? -e : e;
            }
            x_lds[row][q] = acc;
        }
        __syncthreads();
    }

    // output = H[:,4] * float(pi - eps_f32)
    const float MULT = 3.14159253589793f;
    if (tid < 64) out[rowbase + tid] = x_lds[tid][4] * MULT;
}

// ---------------- launcher ------------------------------------------------
extern "C" void kernel_launch(void* const* d_in, const int* in_sizes, int n_in,
                              void* d_out, int out_size, void* d_ws, size_t ws_size,
                              hipStream_t stream) {
    const float* x     = (const float*)d_in[0];   // (32768, 8) fp32
    const float* theta = (const float*)d_in[1];   // (4, 4, 8, 3) fp32
    float* out = (float*)d_out;                   // (32768,) fp32

    char*   ws  = (char*)d_ws;
    float*  gt  = (float*)ws;                         // 4 KB
    ushort* Upr = (ushort*)(ws + 4096);               // 512 KB fragment-major
    ushort* Upi = (ushort*)(ws + 4096 + 524288);      // 512 KB

    gate_table_k<<<1, 128, 0, stream>>>(theta, gt);
    ubuild_k<<<256, 256, 0, stream>>>(gt, Upr, Upi);
    vqc_mfma_k<<<512, 512, 0, stream>>>(x, Upr, Upi, out);
}